// Round 3
// baseline (132.866 us; speedup 1.0000x reference)
//
#include <hip/hip_runtime.h>
#include <hip/hip_bf16.h>
#include <cstdint>
#include <cstddef>

// out = (A2 @ E^T) @ W^T, A2[i,j] = a[i-j] lower-tri Toeplitz,
//   a[d] = (d/4096 + 1e-8)^0.2, a[0] = 1e-8^0.2
// gemm_a: T[i,e] = sum_{j<=i} a[i-j] * E[e,j]  (tri, variable split-j)
// gemm_b: out[i,v] = sum_p Tp[i,e] * W[v,e]
// Round 9: reverted fusion (cross-XCD staleness -> partial corruption).
// New gemm_a schedule: rows I>=16 split 4-way (T0..T3, pieces 8..16 steps),
// rows I<16 split 2-way (T0/T1). 768 blocks, biggest pieces first, dynamic
// refill -> per-CU wall ~= 33 balanced steps at full 8-wave occupancy,
// replacing the old parallel-pair max(I+1,32-I) in [17,32] with solo tails.
// bid&7 == nb in both groups preserves per-XCD Eb L2 locality.
// gemm_b reads 2 or 4 T-streams (block-uniform branch on i0 >= 2048).

#define L_SER 4096
#define DEMB  1024
#define DV    1024

#define R_STRIDE 4224   // shift-replica stride of reversed a; 16B-aligned
#define R_O0     4096

typedef __bf16 bf16_t;
typedef __attribute__((ext_vector_type(8))) __bf16 bf16x8;
typedef __attribute__((ext_vector_type(4))) float f32x4;

// direct global->LDS async copy, 16B per lane (dest = uniform base + lane*16)
__device__ __forceinline__ void glds16(const bf16_t* g, bf16_t* l) {
    __builtin_amdgcn_global_load_lds(
        (const __attribute__((address_space(1))) unsigned int*)(const void*)g,
        (__attribute__((address_space(3))) unsigned int*)(void*)l,
        16, 0, 0);
}

// ---------------------------------------------------------------------------
// Fused prep: blocks [0,132) build R; [132,2180) convert E; [2180,2692) convert W.
// ---------------------------------------------------------------------------
__global__ void prep_kernel(const float* __restrict__ E, const float* __restrict__ W,
                            bf16_t* __restrict__ Eb, bf16_t* __restrict__ Wb,
                            bf16_t* __restrict__ R) {
    const int b = blockIdx.x;
    if (b < 132) {                       // 132*256 = 33792 = 8*4224 exact
        int idx = b * 256 + threadIdx.x;
        int s = idx / R_STRIDE;
        int x = idx - s * R_STRIDE;
        int d = R_O0 + s - x;
        float v = 0.0f;
        if (d >= 0 && d < L_SER)
            v = powf((d == 0) ? 1e-8f : ((float)d * (1.0f / (float)L_SER) + 1e-8f), 0.2f);
        R[idx] = (bf16_t)v;
    } else if (b < 132 + 2048) {         // E: 2048*256*8 = 4194304 elems exact
        int idx = (b - 132) * 256 + threadIdx.x;
        const f32x4* s = (const f32x4*)E;
        f32x4 v0 = s[idx * 2], v1 = s[idx * 2 + 1];
        bf16x8 o;
        o[0] = (bf16_t)v0[0]; o[1] = (bf16_t)v0[1]; o[2] = (bf16_t)v0[2]; o[3] = (bf16_t)v0[3];
        o[4] = (bf16_t)v1[0]; o[5] = (bf16_t)v1[1]; o[6] = (bf16_t)v1[2]; o[7] = (bf16_t)v1[3];
        ((bf16x8*)Eb)[idx] = o;
    } else {                             // W: 512*256*8 = 1048576 elems exact
        int idx = (b - 2180) * 256 + threadIdx.x;
        const f32x4* s = (const f32x4*)W;
        f32x4 v0 = s[idx * 2], v1 = s[idx * 2 + 1];
        bf16x8 o;
        o[0] = (bf16_t)v0[0]; o[1] = (bf16_t)v0[1]; o[2] = (bf16_t)v0[2]; o[3] = (bf16_t)v0[3];
        o[4] = (bf16_t)v1[0]; o[5] = (bf16_t)v1[1]; o[6] = (bf16_t)v1[2]; o[7] = (bf16_t)v1[3];
        ((bf16x8*)Wb)[idx] = o;
    }
}

// ---------------------------------------------------------------------------
// gemm_a: BM=128, BN=128, BK=64, variable split-j (see header). 768 blocks.
// Double-buffered LDS, one barrier per K-step, width-16 global_load_lds
// staging; LDS linear [row][64], XOR chunk swizzle on BOTH sides (rule 21).
// ---------------------------------------------------------------------------
#define GA_STAGE(SBOFS)                                                      \
    _Pragma("unroll")                                                        \
    for (int c = 0; c < 4; ++c) {                                            \
        glds16(pA[c], &sA[(SBOFS) + (c * 32 + wave * 8) * 64]);              \
        glds16(pB[c], &sB[(SBOFS) + (c * 32 + wave * 8) * 64]);              \
        pA[c] += 64; pB[c] += 64;                                            \
    }

#define GA_COMPUTE(SBOFS)                                                    \
    _Pragma("unroll")                                                        \
    for (int kk = 0; kk < 2; ++kk) {                                         \
        const int co = kk ? coff1 : coff0;                                   \
        bf16x8 afr[4], bfr[4];                                               \
        _Pragma("unroll")                                                    \
        for (int tm = 0; tm < 4; ++tm)                                       \
            afr[tm] = *(const bf16x8*)&sA[(SBOFS) + (wm * 64 + tm * 16 + ln) * 64 + co]; \
        _Pragma("unroll")                                                    \
        for (int tn = 0; tn < 4; ++tn)                                       \
            bfr[tn] = *(const bf16x8*)&sB[(SBOFS) + (wn * 64 + tn * 16 + ln) * 64 + co]; \
        _Pragma("unroll")                                                    \
        for (int tm = 0; tm < 4; ++tm)                                       \
            _Pragma("unroll")                                                \
            for (int tn = 0; tn < 4; ++tn)                                   \
                acc[tm][tn] = __builtin_amdgcn_mfma_f32_16x16x32_bf16(afr[tm], bfr[tn], acc[tm][tn], 0, 0, 0); \
    }

__global__ __launch_bounds__(256, 2) void gemm_a_kernel(const bf16_t* __restrict__ R,
                                                        const bf16_t* __restrict__ Eb,
                                                        bf16_t* __restrict__ T0,
                                                        bf16_t* __restrict__ T1,
                                                        bf16_t* __restrict__ T2,
                                                        bf16_t* __restrict__ T3) {
    __shared__ __align__(16) bf16_t sA[2 * 128 * 64];   // 32 KB
    __shared__ __align__(16) bf16_t sB[2 * 128 * 64];   // 32 KB

    // ---- work decomposition -------------------------------------------------
    // bid < 512: rows I in [16,32): bid = (31-I)*32 + p*8 + nb, 4 pieces/tile.
    //   TC = 2(I+1) chunks; piece p: cnt = q + (p<rr), cs = p*q + min(p,rr)
    //   with q = TC>>2, rr = TC&3 (rr in {0,2}).  cnt in [8,16].
    // bid >= 512: rows I in [0,16): s = bid-512 = (15-I)*16 + h*8 + nb,
    //   2 pieces/tile: cnt = I+1, cs = h*(I+1).  cnt in [1,16].
    // Both groups: bid&7 == nb (XCD keeps one Eb panel).
    const int bid = blockIdx.x;
    int I, nb, p, cs, cnt;
    if (bid < 512) {
        nb = bid & 7;
        p  = (bid >> 3) & 3;
        I  = 31 - (bid >> 5);
        int TC = 2 * (I + 1);
        int q = TC >> 2, rr = TC & 3;
        cnt = q + (p < rr ? 1 : 0);
        cs  = p * q + (p < rr ? p : rr);
    } else {
        int s = bid - 512;
        nb = s & 7;
        p  = (s >> 3) & 1;
        I  = 15 - (s >> 4);
        cnt = I + 1;
        cs  = p * (I + 1);
    }
    const int i0 = I * 128;
    const int n0 = nb * 128;
    const int nsteps = cnt;
    const int j0b = cs * 64;
    bf16_t* __restrict__ Tout = (p == 0) ? T0 : (p == 1) ? T1 : (p == 2) ? T2 : T3;

    const int tid  = threadIdx.x;
    const int wave = tid >> 6;
    const int lane = tid & 63;
    const int quad = lane >> 4;
    const int ln   = lane & 15;
    const int wm   = wave >> 1;
    const int wn   = wave & 1;

    // staging lane decomposition: row-in-group = lane>>3, swizzled chunk
    const int lrow = lane >> 3;                 // 0..7
    const int lch  = (lane & 7) ^ lrow;         // source chunk (0..7), XOR swizzle
    // fragment-read swizzled chunk offsets (elems): chunk = (kk*4+quad) ^ (row&7)
    const int rsw   = ln & 7;                   // row&7 for all fragment rows
    const int coff0 = ((quad ^ rsw)) * 8;       // kk = 0
    const int coff1 = (((4 + quad) ^ rsw)) * 8; // kk = 1

    f32x4 acc[4][4];
#pragma unroll
    for (int a = 0; a < 4; ++a)
#pragma unroll
        for (int b = 0; b < 4; ++b) acc[a][b] = (f32x4){0, 0, 0, 0};

    // A row r: replica s=r&7, back-off 8*(r>>3):
    //   elem (r, col) at step j0 = R[s][R_O0 - (i0-j0) - 8*(r>>3) + col]
    const bf16_t* pA[4];
    const bf16_t* pB[4];
#pragma unroll
    for (int c = 0; c < 4; ++c) {
        int r = c * 32 + wave * 8 + lrow;
        pA[c] = R + (size_t)(r & 7) * R_STRIDE + (R_O0 - i0 + j0b - 8 * (r >> 3) + lch * 8);
        pB[c] = Eb + (size_t)(n0 + r) * L_SER + j0b + lch * 8;
    }

    GA_STAGE(0)                                  // step 0 -> buf0
    for (int s = 0;; s += 2) {
        __syncthreads();                         // drains buf0 stage
        if (s + 1 < nsteps) { GA_STAGE(128 * 64) }
        GA_COMPUTE(0)
        if (s + 1 >= nsteps) break;
        __syncthreads();                         // drains buf1 stage
        if (s + 2 < nsteps) { GA_STAGE(0) }
        GA_COMPUTE(128 * 64)
        if (s + 2 >= nsteps) break;
    }

    // C/D: col = ln, row = quad*4 + r (m89-verified)
#pragma unroll
    for (int tm = 0; tm < 4; ++tm) {
        int row_base = i0 + wm * 64 + tm * 16 + quad * 4;
#pragma unroll
        for (int tn = 0; tn < 4; ++tn) {
            int col = n0 + wn * 64 + tn * 16 + ln;
#pragma unroll
            for (int r = 0; r < 4; ++r)
                Tout[(size_t)(row_base + r) * DEMB + col] = (bf16_t)acc[tm][tn][r];
        }
    }
}

// ---------------------------------------------------------------------------
// gemm_b: out[i,v] = sum_p Tp[i,e] * W[v,e]. BM=64, BN=128, BK=64, K=1024.
// 512 blocks (2/CU). B staged via global_load_lds (swizzled source); A
// (T-stream add, 2 or 4 streams by block-uniform i0>=2048) reg-staged with
// swizzled ds_write.
// ---------------------------------------------------------------------------
#define GB_STAGE_A(SBOFS, RA)                                                \
    _Pragma("unroll")                                                        \
    for (int c = 0; c < 2; ++c)                                              \
        *(bf16x8*)&sA[(SBOFS) + aofs[c]] = RA[c];

#define GB_LOAD_A(RA)                                                        \
    _Pragma("unroll")                                                        \
    for (int c = 0; c < 2; ++c) {                                            \
        bf16x8 t0 = *(const bf16x8*)p0[c];                                   \
        bf16x8 t1 = *(const bf16x8*)p1[c];                                   \
        bf16x8 o;                                                            \
        if (fourway) {                                                       \
            bf16x8 t2 = *(const bf16x8*)p2[c];                               \
            bf16x8 t3 = *(const bf16x8*)p3[c];                               \
            _Pragma("unroll")                                                \
            for (int u = 0; u < 8; ++u)                                      \
                o[u] = (bf16_t)(((float)t0[u] + (float)t1[u]) +              \
                                ((float)t2[u] + (float)t3[u]));              \
            p2[c] += 64; p3[c] += 64;                                        \
        } else {                                                             \
            _Pragma("unroll")                                                \
            for (int u = 0; u < 8; ++u)                                      \
                o[u] = (bf16_t)((float)t0[u] + (float)t1[u]);                \
        }                                                                    \
        RA[c] = o;                                                           \
        p0[c] += 64; p1[c] += 64;                                            \
    }

#define GB_STAGE_B(SBOFS)                                                    \
    _Pragma("unroll")                                                        \
    for (int c = 0; c < 4; ++c) {                                            \
        glds16(pW[c], &sB[(SBOFS) + (c * 32 + wave * 8) * 64]);              \
        pW[c] += 64;                                                         \
    }

#define GB_COMPUTE(SBOFS_A, SBOFS_B)                                         \
    _Pragma("unroll")                                                        \
    for (int kk = 0; kk < 2; ++kk) {                                         \
        const int co = kk ? coff1 : coff0;                                   \
        bf16x8 afr[2], bfr[4];                                               \
        _Pragma("unroll")                                                    \
        for (int tm = 0; tm < 2; ++tm)                                       \
            afr[tm] = *(const bf16x8*)&sA[(SBOFS_A) + (wm * 32 + tm * 16 + ln) * 64 + co]; \
        _Pragma("unroll")                                                    \
        for (int tn = 0; tn < 4; ++tn)                                       \
            bfr[tn] = *(const bf16x8*)&sB[(SBOFS_B) + (wn * 64 + tn * 16 + ln) * 64 + co]; \
        _Pragma("unroll")                                                    \
        for (int tm = 0; tm < 2; ++tm)                                       \
            _Pragma("unroll")                                                \
            for (int tn = 0; tn < 4; ++tn)                                   \
                acc[tm][tn] = __builtin_amdgcn_mfma_f32_16x16x32_bf16(afr[tm], bfr[tn], acc[tm][tn], 0, 0, 0); \
    }

__global__ __launch_bounds__(256, 2) void gemm_b_kernel(const bf16_t* __restrict__ T0,
                                                        const bf16_t* __restrict__ T1,
                                                        const bf16_t* __restrict__ T2,
                                                        const bf16_t* __restrict__ T3,
                                                        const bf16_t* __restrict__ Wb,
                                                        float* __restrict__ out) {
    __shared__ __align__(16) bf16_t sA[2 * 64 * 64];    // 16 KB
    __shared__ __align__(16) bf16_t sB[2 * 128 * 64];   // 32 KB

    const int bid = blockIdx.x;
    const int ib = bid >> 3;        // 0..63
    const int nb = bid & 7;
    const int i0 = ib * 64;
    const int n0 = nb * 128;
    const bool fourway = (i0 >= 2048);   // rows I>=16 have 4 partials

    const int tid  = threadIdx.x;
    const int wave = tid >> 6;
    const int lane = tid & 63;
    const int quad = lane >> 4;
    const int ln   = lane & 15;
    const int wm   = wave >> 1;     // 0..1 over 64 m
    const int wn   = wave & 1;      // 0..1 over 128 n
    const int srow = tid >> 3;      // 0..31
    const int t8   = tid & 7;

    const int lrow = lane >> 3;
    const int lch  = (lane & 7) ^ lrow;
    const int rsw   = ln & 7;
    const int coff0 = ((quad ^ rsw)) * 8;
    const int coff1 = (((4 + quad) ^ rsw)) * 8;

    // swizzled A-stage offsets (elems): row = c*32+srow, slot = t8 ^ (row&7)
    int aofs[2];
#pragma unroll
    for (int c = 0; c < 2; ++c)
        aofs[c] = (c * 32 + srow) * 64 + (t8 ^ (srow & 7)) * 8;

    f32x4 acc[2][4];
#pragma unroll
    for (int a = 0; a < 2; ++a)
#pragma unroll
        for (int b = 0; b < 4; ++b) acc[a][b] = (f32x4){0, 0, 0, 0};

    const int nsteps = DEMB / 64;   // 16 (even)

    const bf16_t* p0[2];
    const bf16_t* p1[2];
    const bf16_t* p2[2];
    const bf16_t* p3[2];
    const bf16_t* pW[4];
    bf16x8 ra0[2], ra1[2];
#pragma unroll
    for (int c = 0; c < 2; ++c) {
        size_t arow = (size_t)(i0 + c * 32 + srow) * DEMB + t8 * 8;
        p0[c] = T0 + arow;
        p1[c] = T1 + arow;
        p2[c] = T2 + arow;
        p3[c] = T3 + arow;
    }
#pragma unroll
    for (int c = 0; c < 4; ++c)
        pW[c] = Wb + (size_t)(n0 + c * 32 + wave * 8 + lrow) * DEMB + lch * 8;

    GB_LOAD_A(ra0)          // step 0
    GB_LOAD_A(ra1)          // step 1
    GB_STAGE_B(0)           // step 0 -> bufB0

    for (int s = 0;; s += 2) {
        GB_STAGE_A(0, ra0)
        __syncthreads();                              // A(s) visible; B(s) drained
        if (s + 2 < nsteps) { GB_LOAD_A(ra0) }
        if (s + 1 < nsteps) { GB_STAGE_B(128 * 64) }
        GB_COMPUTE(0, 0)
        // nsteps even: no break needed after phase 0
        GB_STAGE_A(64 * 64, ra1)
        __syncthreads();                              // A(s+1) visible; B(s+1) drained
        if (s + 3 < nsteps) { GB_LOAD_A(ra1) }
        if (s + 2 < nsteps) { GB_STAGE_B(0) }
        GB_COMPUTE(64 * 64, 128 * 64)
        if (s + 2 >= nsteps) break;
    }

#pragma unroll
    for (int tm = 0; tm < 2; ++tm) {
        int row_base = i0 + wm * 32 + tm * 16 + quad * 4;
#pragma unroll
        for (int tn = 0; tn < 4; ++tn) {
            int col = n0 + wn * 64 + tn * 16 + ln;
#pragma unroll
            for (int r = 0; r < 4; ++r)
                out[(size_t)(row_base + r) * DV + col] = acc[tm][tn][r];
        }
    }
}

// ---------------------------------------------------------------------------
extern "C" void kernel_launch(void* const* d_in, const int* in_sizes, int n_in,
                              void* d_out, int out_size, void* d_ws, size_t ws_size,
                              hipStream_t stream) {
    const float* E = (const float*)d_in[0];   // (1024, 4096) f32
    const float* W = (const float*)d_in[1];   // (1024, 1024) f32
    float* out = (float*)d_out;               // (4096, 1024) f32

    char* ws = (char*)d_ws;
    bf16_t* Eb = (bf16_t*)(ws);                               // 8 MB
    bf16_t* T0 = (bf16_t*)(ws + (size_t)8  * 1024 * 1024);    // 8 MB
    bf16_t* T1 = (bf16_t*)(ws + (size_t)16 * 1024 * 1024);    // 8 MB
    bf16_t* T2 = (bf16_t*)(ws + (size_t)24 * 1024 * 1024);    // 8 MB
    bf16_t* T3 = (bf16_t*)(ws + (size_t)32 * 1024 * 1024);    // 8 MB
    bf16_t* Wb = (bf16_t*)(ws + (size_t)40 * 1024 * 1024);    // 2 MB
    bf16_t* R  = (bf16_t*)(ws + (size_t)42 * 1024 * 1024);    // 66 KB

    prep_kernel<<<2692, 256, 0, stream>>>(E, W, Eb, Wb, R);
    gemm_a_kernel<<<768, 256, 0, stream>>>(R, Eb, T0, T1, T2, T3);
    gemm_b_kernel<<<512, 256, 0, stream>>>(T0, T1, T2, T3, Wb, out);
}

// Round 4
// 125.884 us; speedup vs baseline: 1.0555x; 1.0555x over previous
//
#include <hip/hip_runtime.h>
#include <hip/hip_bf16.h>
#include <cstdint>
#include <cstddef>

// out = (A2 @ E^T) @ W^T, A2[i,j] = a[i-j] lower-tri Toeplitz,
//   a[d] = (d/4096 + 1e-8)^0.2, a[0] = 1e-8^0.2
// gemm_a: T[i,e] = sum_{j<=i} a[i-j] * E[e,j]  (tri, split-j -> T0 + T1)
// tsum:   Tsum = T0 + T1 (bf16, vectorized; removes the add from gemm_b's loop)
// gemm_b: out[i,v] = sum_e Tsum[i,e] * W[v,e]  (pure all-glds16 GEMM)
// Round 10: reverted R3's 4-way split (regression: +traffic, +VALU in gemm_b,
// +256 epilogues; R1's complementary pairing was already balanced at 33
// steps/CU). New: gemm_b was VALU-bound on the T0+T1 reg-staged add
// (~640 VALU-cyc/SIMD vs 621 MFMA cyc per step) -> hoisted into a 4us
// bandwidth-bound tsum pass; gemm_b is now a pure m97-style GEMM with both
// operands via width-16 global_load_lds and the both-sides XOR swizzle.

#define L_SER 4096
#define DEMB  1024
#define DV    1024

#define R_STRIDE 4224   // shift-replica stride of reversed a; 16B-aligned
#define R_O0     4096

typedef __bf16 bf16_t;
typedef __attribute__((ext_vector_type(8))) __bf16 bf16x8;
typedef __attribute__((ext_vector_type(4))) float f32x4;

// direct global->LDS async copy, 16B per lane (dest = uniform base + lane*16)
__device__ __forceinline__ void glds16(const bf16_t* g, bf16_t* l) {
    __builtin_amdgcn_global_load_lds(
        (const __attribute__((address_space(1))) unsigned int*)(const void*)g,
        (__attribute__((address_space(3))) unsigned int*)(void*)l,
        16, 0, 0);
}

// ---------------------------------------------------------------------------
// Fused prep: blocks [0,132) build R; [132,2180) convert E; [2180,2692) convert W.
// ---------------------------------------------------------------------------
__global__ void prep_kernel(const float* __restrict__ E, const float* __restrict__ W,
                            bf16_t* __restrict__ Eb, bf16_t* __restrict__ Wb,
                            bf16_t* __restrict__ R) {
    const int b = blockIdx.x;
    if (b < 132) {                       // 132*256 = 33792 = 8*4224 exact
        int idx = b * 256 + threadIdx.x;
        int s = idx / R_STRIDE;
        int x = idx - s * R_STRIDE;
        int d = R_O0 + s - x;
        float v = 0.0f;
        if (d >= 0 && d < L_SER)
            v = powf((d == 0) ? 1e-8f : ((float)d * (1.0f / (float)L_SER) + 1e-8f), 0.2f);
        R[idx] = (bf16_t)v;
    } else if (b < 132 + 2048) {         // E: 2048*256*8 = 4194304 elems exact
        int idx = (b - 132) * 256 + threadIdx.x;
        const f32x4* s = (const f32x4*)E;
        f32x4 v0 = s[idx * 2], v1 = s[idx * 2 + 1];
        bf16x8 o;
        o[0] = (bf16_t)v0[0]; o[1] = (bf16_t)v0[1]; o[2] = (bf16_t)v0[2]; o[3] = (bf16_t)v0[3];
        o[4] = (bf16_t)v1[0]; o[5] = (bf16_t)v1[1]; o[6] = (bf16_t)v1[2]; o[7] = (bf16_t)v1[3];
        ((bf16x8*)Eb)[idx] = o;
    } else {                             // W: 512*256*8 = 1048576 elems exact
        int idx = (b - 2180) * 256 + threadIdx.x;
        const f32x4* s = (const f32x4*)W;
        f32x4 v0 = s[idx * 2], v1 = s[idx * 2 + 1];
        bf16x8 o;
        o[0] = (bf16_t)v0[0]; o[1] = (bf16_t)v0[1]; o[2] = (bf16_t)v0[2]; o[3] = (bf16_t)v0[3];
        o[4] = (bf16_t)v1[0]; o[5] = (bf16_t)v1[1]; o[6] = (bf16_t)v1[2]; o[7] = (bf16_t)v1[3];
        ((bf16x8*)Wb)[idx] = o;
    }
}

// ---------------------------------------------------------------------------
// tsum: Tsum = T0 + T1, bf16x8 vectorized. 4096*1024 elems = 524288 x bf16x8.
// ---------------------------------------------------------------------------
__global__ void tsum_kernel(const bf16_t* __restrict__ T0, const bf16_t* __restrict__ T1,
                            bf16_t* __restrict__ Tsum) {
    int idx = blockIdx.x * 256 + threadIdx.x;     // 2048 blocks x 256 = 524288
    bf16x8 t0 = ((const bf16x8*)T0)[idx];
    bf16x8 t1 = ((const bf16x8*)T1)[idx];
    bf16x8 o;
#pragma unroll
    for (int u = 0; u < 8; ++u) o[u] = (bf16_t)((float)t0[u] + (float)t1[u]);
    ((bf16x8*)Tsum)[idx] = o;
}

// ---------------------------------------------------------------------------
// gemm_a: BM=128, BN=128, BK=64, split-j. 512 blocks (2/CU); pair (bid,bid+256)
// shares a CU -> per-CU work = (I+1) + (32-I) = 33 steps. Double-buffered LDS,
// one barrier per K-step, width-16 global_load_lds staging (swizzled source).
// LDS linear [row][64], XOR chunk swizzle on BOTH sides (rule 21).
// ---------------------------------------------------------------------------
#define GA_STAGE(SBOFS)                                                      \
    _Pragma("unroll")                                                        \
    for (int c = 0; c < 4; ++c) {                                            \
        glds16(pA[c], &sA[(SBOFS) + (c * 32 + wave * 8) * 64]);              \
        glds16(pB[c], &sB[(SBOFS) + (c * 32 + wave * 8) * 64]);              \
        pA[c] += 64; pB[c] += 64;                                            \
    }

#define GA_COMPUTE(SBOFS)                                                    \
    _Pragma("unroll")                                                        \
    for (int kk = 0; kk < 2; ++kk) {                                         \
        const int co = kk ? coff1 : coff0;                                   \
        bf16x8 afr[4], bfr[4];                                               \
        _Pragma("unroll")                                                    \
        for (int tm = 0; tm < 4; ++tm)                                       \
            afr[tm] = *(const bf16x8*)&sA[(SBOFS) + (wm * 64 + tm * 16 + ln) * 64 + co]; \
        _Pragma("unroll")                                                    \
        for (int tn = 0; tn < 4; ++tn)                                       \
            bfr[tn] = *(const bf16x8*)&sB[(SBOFS) + (wn * 64 + tn * 16 + ln) * 64 + co]; \
        _Pragma("unroll")                                                    \
        for (int tm = 0; tm < 4; ++tm)                                       \
            _Pragma("unroll")                                                \
            for (int tn = 0; tn < 4; ++tn)                                   \
                acc[tm][tn] = __builtin_amdgcn_mfma_f32_16x16x32_bf16(afr[tm], bfr[tn], acc[tm][tn], 0, 0, 0); \
    }

__global__ __launch_bounds__(256, 2) void gemm_a_kernel(const bf16_t* __restrict__ R,
                                                        const bf16_t* __restrict__ Eb,
                                                        bf16_t* __restrict__ T0,
                                                        bf16_t* __restrict__ T1) {
    __shared__ __align__(16) bf16_t sA[2 * 128 * 64];   // 32 KB
    __shared__ __align__(16) bf16_t sB[2 * 128 * 64];   // 32 KB

    const int bid = blockIdx.x;
    int I, nb, h;
    if (bid < 256) { I = bid >> 3;                nb = bid & 7;         h = 0; }
    else           { I = 31 - ((bid - 256) >> 3); nb = (bid - 256) & 7; h = 1; }
    const int i0 = I * 128;
    const int n0 = nb * 128;
    const int nsteps = I + 1;
    const int j0b = h ? 64 * (I + 1) : 0;
    bf16_t* __restrict__ Tout = h ? T1 : T0;

    const int tid  = threadIdx.x;
    const int wave = tid >> 6;
    const int lane = tid & 63;
    const int quad = lane >> 4;
    const int ln   = lane & 15;
    const int wm   = wave >> 1;
    const int wn   = wave & 1;

    // staging lane decomposition: row-in-group = lane>>3, swizzled chunk
    const int lrow = lane >> 3;                 // 0..7
    const int lch  = (lane & 7) ^ lrow;         // source chunk (0..7), XOR swizzle
    // fragment-read swizzled chunk offsets (elems): chunk = (kk*4+quad) ^ (row&7)
    const int rsw   = ln & 7;                   // row&7 for all fragment rows
    const int coff0 = ((quad ^ rsw)) * 8;       // kk = 0
    const int coff1 = (((4 + quad) ^ rsw)) * 8; // kk = 1

    f32x4 acc[4][4];
#pragma unroll
    for (int a = 0; a < 4; ++a)
#pragma unroll
        for (int b = 0; b < 4; ++b) acc[a][b] = (f32x4){0, 0, 0, 0};

    // A row r: replica s=r&7, back-off 8*(r>>3):
    //   elem (r, col) at step j0 = R[s][R_O0 - (i0-j0) - 8*(r>>3) + col]
    const bf16_t* pA[4];
    const bf16_t* pB[4];
#pragma unroll
    for (int c = 0; c < 4; ++c) {
        int r = c * 32 + wave * 8 + lrow;
        pA[c] = R + (size_t)(r & 7) * R_STRIDE + (R_O0 - i0 + j0b - 8 * (r >> 3) + lch * 8);
        pB[c] = Eb + (size_t)(n0 + r) * L_SER + j0b + lch * 8;
    }

    GA_STAGE(0)                                  // step 0 -> buf0
    for (int s = 0;; s += 2) {
        __syncthreads();                         // drains buf0 stage
        if (s + 1 < nsteps) { GA_STAGE(128 * 64) }
        GA_COMPUTE(0)
        if (s + 1 >= nsteps) break;
        __syncthreads();                         // drains buf1 stage
        if (s + 2 < nsteps) { GA_STAGE(0) }
        GA_COMPUTE(128 * 64)
        if (s + 2 >= nsteps) break;
    }

    // C/D: col = ln, row = quad*4 + r (m89-verified)
#pragma unroll
    for (int tm = 0; tm < 4; ++tm) {
        int row_base = i0 + wm * 64 + tm * 16 + quad * 4;
#pragma unroll
        for (int tn = 0; tn < 4; ++tn) {
            int col = n0 + wn * 64 + tn * 16 + ln;
#pragma unroll
            for (int r = 0; r < 4; ++r)
                Tout[(size_t)(row_base + r) * DEMB + col] = (bf16_t)acc[tm][tn][r];
        }
    }
}

// ---------------------------------------------------------------------------
// gemm_b: out[i,v] = sum_e Tsum[i,e] * W[v,e]. BM=64, BN=128, BK=64, K=1024.
// 512 blocks (2/CU). BOTH operands via width-16 global_load_lds (swizzled
// source) -- zero per-step VALU beyond address upkeep.
// ---------------------------------------------------------------------------
#define GB_STAGE(AOFS, BOFS)                                                 \
    _Pragma("unroll")                                                        \
    for (int c = 0; c < 2; ++c) {                                            \
        glds16(pT[c], &sA[(AOFS) + (c * 32 + wave * 8) * 64]);               \
        pT[c] += 64;                                                         \
    }                                                                        \
    _Pragma("unroll")                                                        \
    for (int c = 0; c < 4; ++c) {                                            \
        glds16(pW[c], &sB[(BOFS) + (c * 32 + wave * 8) * 64]);               \
        pW[c] += 64;                                                         \
    }

#define GB_COMPUTE(AOFS, BOFS)                                               \
    _Pragma("unroll")                                                        \
    for (int kk = 0; kk < 2; ++kk) {                                         \
        const int co = kk ? coff1 : coff0;                                   \
        bf16x8 afr[2], bfr[4];                                               \
        _Pragma("unroll")                                                    \
        for (int tm = 0; tm < 2; ++tm)                                       \
            afr[tm] = *(const bf16x8*)&sA[(AOFS) + (wm * 32 + tm * 16 + ln) * 64 + co]; \
        _Pragma("unroll")                                                    \
        for (int tn = 0; tn < 4; ++tn)                                       \
            bfr[tn] = *(const bf16x8*)&sB[(BOFS) + (wn * 64 + tn * 16 + ln) * 64 + co]; \
        _Pragma("unroll")                                                    \
        for (int tm = 0; tm < 2; ++tm)                                       \
            _Pragma("unroll")                                                \
            for (int tn = 0; tn < 4; ++tn)                                   \
                acc[tm][tn] = __builtin_amdgcn_mfma_f32_16x16x32_bf16(afr[tm], bfr[tn], acc[tm][tn], 0, 0, 0); \
    }

__global__ __launch_bounds__(256, 2) void gemm_b_kernel(const bf16_t* __restrict__ Tsum,
                                                        const bf16_t* __restrict__ Wb,
                                                        float* __restrict__ out) {
    __shared__ __align__(16) bf16_t sA[2 * 64 * 64];    // 16 KB
    __shared__ __align__(16) bf16_t sB[2 * 128 * 64];   // 32 KB

    const int bid = blockIdx.x;
    const int ib = bid >> 3;        // 0..63
    const int nb = bid & 7;
    const int i0 = ib * 64;
    const int n0 = nb * 128;

    const int tid  = threadIdx.x;
    const int wave = tid >> 6;
    const int lane = tid & 63;
    const int quad = lane >> 4;
    const int ln   = lane & 15;
    const int wm   = wave >> 1;     // 0..1 over 64 m
    const int wn   = wave & 1;      // 0..1 over 128 n

    const int lrow = lane >> 3;
    const int lch  = (lane & 7) ^ lrow;
    const int rsw   = ln & 7;
    const int coff0 = ((quad ^ rsw)) * 8;
    const int coff1 = (((4 + quad) ^ rsw)) * 8;

    f32x4 acc[2][4];
#pragma unroll
    for (int a = 0; a < 2; ++a)
#pragma unroll
        for (int b = 0; b < 4; ++b) acc[a][b] = (f32x4){0, 0, 0, 0};

    const int nsteps = DEMB / 64;   // 16 (even)

    const bf16_t* pT[2];
    const bf16_t* pW[4];
#pragma unroll
    for (int c = 0; c < 2; ++c)
        pT[c] = Tsum + (size_t)(i0 + c * 32 + wave * 8 + lrow) * DEMB + lch * 8;
#pragma unroll
    for (int c = 0; c < 4; ++c)
        pW[c] = Wb + (size_t)(n0 + c * 32 + wave * 8 + lrow) * DEMB + lch * 8;

    GB_STAGE(0, 0)                                // step 0 -> buf0
    for (int s = 0;; s += 2) {
        __syncthreads();                          // drains buf0 stage
        if (s + 1 < nsteps) { GB_STAGE(64 * 64, 128 * 64) }
        GB_COMPUTE(0, 0)
        if (s + 1 >= nsteps) break;
        __syncthreads();                          // drains buf1 stage
        if (s + 2 < nsteps) { GB_STAGE(0, 0) }
        GB_COMPUTE(64 * 64, 128 * 64)
        if (s + 2 >= nsteps) break;
    }

#pragma unroll
    for (int tm = 0; tm < 2; ++tm) {
        int row_base = i0 + wm * 32 + tm * 16 + quad * 4;
#pragma unroll
        for (int tn = 0; tn < 4; ++tn) {
            int col = n0 + wn * 64 + tn * 16 + ln;
#pragma unroll
            for (int r = 0; r < 4; ++r)
                out[(size_t)(row_base + r) * DV + col] = acc[tm][tn][r];
        }
    }
}

// ---------------------------------------------------------------------------
extern "C" void kernel_launch(void* const* d_in, const int* in_sizes, int n_in,
                              void* d_out, int out_size, void* d_ws, size_t ws_size,
                              hipStream_t stream) {
    const float* E = (const float*)d_in[0];   // (1024, 4096) f32
    const float* W = (const float*)d_in[1];   // (1024, 1024) f32
    float* out = (float*)d_out;               // (4096, 1024) f32

    char* ws = (char*)d_ws;
    bf16_t* Eb   = (bf16_t*)(ws);                               // 8 MB
    bf16_t* T0   = (bf16_t*)(ws + (size_t)8  * 1024 * 1024);    // 8 MB
    bf16_t* T1   = (bf16_t*)(ws + (size_t)16 * 1024 * 1024);    // 8 MB
    bf16_t* Tsum = (bf16_t*)(ws + (size_t)24 * 1024 * 1024);    // 8 MB
    bf16_t* Wb   = (bf16_t*)(ws + (size_t)32 * 1024 * 1024);    // 2 MB
    bf16_t* R    = (bf16_t*)(ws + (size_t)34 * 1024 * 1024);    // 66 KB

    prep_kernel<<<2692, 256, 0, stream>>>(E, W, Eb, Wb, R);
    gemm_a_kernel<<<512, 256, 0, stream>>>(R, Eb, T0, T1);
    tsum_kernel<<<2048, 256, 0, stream>>>(T0, T1, Tsum);
    gemm_b_kernel<<<512, 256, 0, stream>>>(Tsum, Wb, out);
}